// Round 11
// baseline (292.079 us; speedup 1.0000x reference)
//
#include <hip/hip_runtime.h>
#include <hip/hip_fp16.h>
#include <stdint.h>

#define AS1 __attribute__((address_space(1)))
#define AS3 __attribute__((address_space(3)))

typedef unsigned short u16;
typedef __attribute__((ext_vector_type(8))) _Float16 half8;
typedef __attribute__((ext_vector_type(4))) float f32x4;
typedef __attribute__((ext_vector_type(3))) uint32_t u32x3;

#define LOG2PI_F 1.8378770664093453f

// problem constants
#define BQ   16
#define TQ   256
#define DQ   512
#define LQ   51
#define L2Q  2601
#define KQ   512      // single fp16 x . fp16 W  (xl/Wl terms ~1e-4 << fp16-C rounding)
#define NCOL   15759
#define NPAD   15872  // 124*128
// tiled operand layout (= LDS staging order): [tile][c8(0..63)][row(0..127)][8 u16]
#define TILE_U16  65536
#define TILE_U4   8192
// permuted column layout (baked into B^T row order). t-struct cols are stored
// TRANSFORMED by the gemm epilogue (bias added; fields 3/5 exp'd; field 4 as
// ofac = 0.9*tanh(0.5*u) stored directly). s-block cols stay RAW:
//   col < 15606 : 6*ij + {0:tw, 1:m0, 2:m1, 3:d0, 4:ofac, 5:d1}
//   s-blocks    : sw_raw @ SB0+j, smu_raw @ SB1+j, svar_raw @ SB2+j   (j<51)
#define NSTR 15606
#define SB0  15616
#define SB1  15680
#define SB2  15744
#define SWP  156    // scan LDS s-window pitch (floats)

__device__ __forceinline__ u16 f2h(float f) {
  union { __half h; u16 u; } cv; cv.h = __float2half(f); return cv.u;
}
__device__ __forceinline__ float frcp(float x) { return __builtin_amdgcn_rcpf(x); }
__device__ __forceinline__ float flog(float x) { return __builtin_amdgcn_logf(x) * 0.6931471805599453f; }
__device__ __forceinline__ float h2f(u16 bits) {
  union { u16 u; __half h; } cv; cv.u = bits;
  return __half2float(cv.h);
}
__device__ __forceinline__ float2 cvth2(uint32_t w) {
  return __half22float2(*(const __half2*)&w);
}

// ---------------------------------------------------------------- build A (tiled)
// single fp16: xh = fp16(x).
__global__ __launch_bounds__(256) void build_a_kernel(const float* __restrict__ x,
                                                      u16* __restrict__ A,
                                                      int TC, int lgTC, int nmt) {
  int idx = blockIdx.x * 256 + threadIdx.x;   // exactly 4096*512
  int m = idx >> 9;
  int k = idx & 511;
  float v = x[idx];
  u16 h = f2h(v);
  int b = m >> 8, t = m & 255;
  int c = t >> lgTC;                 // chunk
  int tloc = t & (TC - 1);
  int mloc = b * TC + tloc;          // chunk-local row
  int mt = mloc >> 7, r = mloc & 127;
  u16* tile = A + (size_t)(c * nmt + mt) * TILE_U16 + r * 8;
  int c8 = k >> 3, e = k & 7;
  tile[(size_t)c8 * 1024 + e] = h;
}

// ---------------------------------------------------------------- build B^T (tiled)
// single fp16 Wh. Also emits biasTab[n] (fp32) for the gemm epilogue (y==0).
__global__ __launch_bounds__(256) void build_b_kernel(
    const float* __restrict__ Ws_w, const float* __restrict__ Ws_mu,
    const float* __restrict__ Ws_var, const float* __restrict__ Wt_w,
    const float* __restrict__ Wt_mu, const float* __restrict__ Wt_var,
    const float* __restrict__ bt_w, const float* __restrict__ bt_mu,
    const float* __restrict__ bt_var, u16* __restrict__ BT,
    float* __restrict__ biasTab) {
  int n = blockIdx.x * 256 + threadIdx.x;
  if (n >= NPAD) return;
  const float* src = nullptr;
  int c0 = 0, stride = 0, two = 0;
  int ij = 0, r = 0;
  if (n < NSTR) {
    ij = (int)((unsigned)n / 6u);
    r = n - 6 * ij;
    switch (r) {
      case 0: src = Wt_w;   stride = L2Q;     c0 = ij;         break;
      case 1: src = Wt_mu;  stride = 2 * L2Q; c0 = 2 * ij;     break;
      case 2: src = Wt_mu;  stride = 2 * L2Q; c0 = 2 * ij + 1; break;
      case 3: src = Wt_var; stride = 4 * L2Q; c0 = 4 * ij;     break;
      case 4: src = Wt_var; stride = 4 * L2Q; c0 = 4 * ij + 1; two = 1; break;
      default: src = Wt_var; stride = 4 * L2Q; c0 = 4 * ij + 3; break;
    }
  } else if (n >= SB0 && n < SB0 + LQ) { src = Ws_w;   stride = LQ; c0 = n - SB0; }
  else if (n >= SB1 && n < SB1 + LQ)   { src = Ws_mu;  stride = LQ; c0 = n - SB1; }
  else if (n >= SB2 && n < SB2 + LQ)   { src = Ws_var; stride = LQ; c0 = n - SB2; }
  int kb = blockIdx.y * 8;
  union { u16 u[8]; uint4 v; } H;
#pragma unroll
  for (int t = 0; t < 8; ++t) {
    float w = 0.f;
    if (src) {
      const float* p = src + (size_t)(kb + t) * stride + c0;
      w = p[0];
      if (two) w += p[1];
    }
    H.u[t] = f2h(w);
  }
  int nt = n >> 7, col = n & 127;
  uint4* tb = (uint4*)BT + (size_t)nt * TILE_U4 + col;
  int c8 = kb >> 3;
  tb[(size_t)c8 * 128] = H.v;

  if (blockIdx.y == 0) {
    float bias = 0.f;
    if (n < NSTR) {
      switch (r) {
        case 0: bias = bt_w[ij]; break;
        case 1: bias = bt_mu[2 * ij]; break;
        case 2: bias = bt_mu[2 * ij + 1]; break;
        case 3: bias = bt_var[4 * ij]; break;
        case 4: bias = bt_var[4 * ij + 1] + bt_var[4 * ij + 2]; break;
        default: bias = bt_var[4 * ij + 3]; break;
      }
    }
    biasTab[n] = bias;
  }
}

// ---------------------------------------------------------------- GEMM
// K=512 single-fp16. 256x128 block (wave 128x64), ring-3 BK=32 slots,
// stage-ahead-1, counted vmcnt(6), raw s_barrier, setprio, 16x16x32 f16.
// Epilogue fuses bias + field transform; R11: fc INNERMOST so the 4 stores
// covering one 128B line issue back-to-back (R10 fc-outer left 32B partials
// -> 1.9x HBM write amplification, WRITE_SIZE 245MB vs 130MB logical).
__global__ __launch_bounds__(256, 2) void gemm_kernel(
    const u16* __restrict__ A, const u16* __restrict__ BT,
    const float* __restrict__ biasTab,
    __half* __restrict__ C, int tile0, int lg_nmt2) {
  const int lin = blockIdx.x;
  const int xcd = lin & 7;
  const int s = lin >> 3;
  const int mb = lg_nmt2 < 2 ? lg_nmt2 : 2;
  const int msub = s & ((1 << mb) - 1);
  const int ntsel = (s >> mb) & 15;
  const int mset = s >> (mb + 4);
  const int mtile2 = (mset << mb) + msub;      // 256-row M-block index
  const int ntile = (ntsel << 3) + xcd;
  if (ntile >= 124) return;

  __shared__ uint4 ring[3][1536];   // 72 KB -> 2 blocks/CU
  const int tid = threadIdx.x;
  const int lane = tid & 63;
  const int wave = tid >> 6;
  const int wM = wave >> 1;        // which 128-row A half-tile
  const int wN = wave & 1;         // which 64-col B half
  const int q4 = lane >> 4;
  const int c16 = lane & 15;

  const uint4* At0 = (const uint4*)A + (size_t)(tile0 + mtile2 * 2) * TILE_U4;
  const uint4* At1 = At0 + TILE_U4;
  const uint4* Bt  = (const uint4*)BT + (size_t)ntile * TILE_U4;

  f32x4 acc[8][4];
#pragma unroll
  for (int a_ = 0; a_ < 8; ++a_)
#pragma unroll
    for (int b_ = 0; b_ < 4; ++b_) acc[a_][b_] = (f32x4){0.f, 0.f, 0.f, 0.f};

  AS3 uint4* rg = (AS3 uint4*)&ring[0][0];

#define STAGE_W(slot, h)                                                        \
  {                                                                             \
    _Pragma("unroll")                                                           \
    for (int ss_ = 0; ss_ < 2; ++ss_) {                                         \
      int ca_ = wave * 2 + ss_;                                                 \
      __builtin_amdgcn_global_load_lds(                                         \
          (const AS1 void*)(At0 + (h) * 512 + ca_ * 64 + lane),                 \
          (AS3 void*)(rg + (slot) * 1536 + ca_ * 64), 16, 0, 0);                \
      __builtin_amdgcn_global_load_lds(                                         \
          (const AS1 void*)(At1 + (h) * 512 + ca_ * 64 + lane),                 \
          (AS3 void*)(rg + (slot) * 1536 + 512 + ca_ * 64), 16, 0, 0);          \
      __builtin_amdgcn_global_load_lds(                                         \
          (const AS1 void*)(Bt + (h) * 512 + ca_ * 64 + lane),                  \
          (AS3 void*)(rg + (slot) * 1536 + 1024 + ca_ * 64), 16, 0, 0);         \
    }                                                                           \
  }

  STAGE_W(0, 0);

  int cur = 0;
  for (int h = 0; h < 16; ++h) {
    int nxt = cur + 1; if (nxt == 3) nxt = 0;
    int hs = (h + 1 < 16) ? (h + 1) : 15;
    STAGE_W(nxt, hs);
    asm volatile("s_waitcnt vmcnt(6)" ::: "memory");
    __builtin_amdgcn_s_barrier();   // all waves' window-h loads now visible

    const uint4* sa = &ring[cur][wM * 512];
    const uint4* sb = &ring[cur][1024];
    half8 af[8], bfv[4];
#pragma unroll
    for (int f = 0; f < 8; ++f)
      af[f] = *(const half8*)&sa[q4 * 128 + f * 16 + c16];
#pragma unroll
    for (int g = 0; g < 4; ++g)
      bfv[g] = *(const half8*)&sb[q4 * 128 + wN * 64 + g * 16 + c16];
    __builtin_amdgcn_s_setprio(1);
#pragma unroll
    for (int fr = 0; fr < 8; ++fr)
#pragma unroll
      for (int fc = 0; fc < 4; ++fc)
        acc[fr][fc] = __builtin_amdgcn_mfma_f32_16x16x32_f16(af[fr], bfv[fc],
                                                             acc[fr][fc], 0, 0, 0);
    __builtin_amdgcn_s_setprio(0);
    cur = nxt;
  }
#undef STAGE_W

  // epilogue: fused bias + field transform, fp16 store, fc innermost.
  // r0..2: +bias raw; r3,r5: exp(clamp(v+bias,+-1));
  // r4: ofac = 0.9*(E-1)/(E+1), E = exp(clamp(v+bias,+-11)).
  int colv[4]; float biasv[4], clv[4]; int dDv[4], dOv[4];
#pragma unroll
  for (int fc = 0; fc < 4; ++fc) {
    int col = ntile * 128 + wN * 64 + fc * 16 + c16;
    colv[fc] = col;
    biasv[fc] = biasTab[col];
    unsigned uc = (unsigned)col;
    unsigned ij6 = uc / 6u;
    int r = (int)(uc - 6u * ij6);
    dDv[fc] = (col < NSTR) && (r == 3 || r == 5);
    dOv[fc] = (col < NSTR) && (r == 4);
    clv[fc] = dOv[fc] ? 11.f : 1.f;
  }
#pragma unroll
  for (int fr = 0; fr < 8; ++fr) {
    int growb = (mtile2 * 2 + wM) * 128 + fr * 16 + q4 * 4;
#pragma unroll
    for (int i = 0; i < 4; ++i) {
      size_t rowoff = (size_t)(growb + i) * NPAD;
#pragma unroll
      for (int fc = 0; fc < 4; ++fc) {
        float v = acc[fr][fc][i] + biasv[fc];
        float e = __expf(fminf(fmaxf(v, -clv[fc]), clv[fc]));
        float of = 0.9f * (e - 1.f) * frcp(e + 1.f);
        v = dDv[fc] ? e : (dOv[fc] ? of : v);
        C[rowoff + colv[fc]] = __float2half(v);
      }
    }
  }
}

// ---------------------------------------------------------------- scan
struct Vals { float sw, smu, svar, tw, m0, m1, d0, ofac, d1; };

// log-combined merge2: the four flog() of the original collapse to one
// flog(det*nvar*den*la)  (all factors > 0; derivation checked vs original).
template <bool CHILD>
__device__ __forceinline__ float merge2(const Vals& v, float nmu, float nvar,
                                        float& mu_n, float& var_n) {
  float off = v.ofac * __builtin_amdgcn_sqrtf(v.d0 * v.d1);
  float det = fmaf(v.d0, v.d1, -off * off);
  float inv = frcp(det);
  float a = v.d1 * inv, bo = -off * inv, d = v.d0 * inv;
  float e0 = a * v.m0 + bo * v.m1;
  float e1 = bo * v.m0 + d * v.m1;
  float quad1 = e0 * e0 * v.d0 + 2.f * e0 * e1 * off + e1 * e1 * v.d1;
  float l2 = frcp(nvar);
  float eta2 = nmu * l2;
  float den, keep, es, la;
  if (CHILD) { den = d + l2; keep = e0; es = e1 + eta2; }
  else       { den = a + l2; keep = e1; es = e0 + eta2; }
  float rden = frcp(den);
  if (CHILD) la = a - bo * bo * rden;
  else       la = d - bo * bo * rden;
  float etan = keep - bo * rden * es;
  var_n = frcp(la);
  mu_n = var_n * etan;
  float lp = det * nvar;
  lp *= den;
  lp *= la;
  return -0.5f * (LOG2PI_F + flog(lp) + quad1 + nmu * eta2 - es * es * rden -
                  etan * etan * var_n);
}

// decode: all fields pre-transformed by the gemm epilogue -> pure converts.
__device__ __forceinline__ Vals decode_t(u32x3 cr) {
  float2 p0 = cvth2(cr.x);
  float2 p1 = cvth2(cr.y);
  float2 p2 = cvth2(cr.z);
  Vals cur;
  cur.tw = p0.x;
  cur.m0 = p0.y;
  cur.m1 = p1.x;
  cur.d0 = p1.y;
  cur.ofac = p2.x;                      // 0.9*tanh stored directly
  cur.d1 = p2.y;
  cur.sw = 0.f; cur.smu = 0.f; cur.svar = 1.f;
  return cur;
}

// s-window staging, split issue-early / write-late (T14).
// 16 rows x 3 segs x 64 cols (51 valid) = 16*96 u32 = 1536 = 6/thread.
__device__ __forceinline__ void s_issue(uint32_t r[6], const u16* __restrict__ base,
                                        int w16, int tid) {
#pragma unroll
  for (int p = 0; p < 6; ++p) {
    int idx = tid + p * 256;
    int tt = (int)((unsigned)idx / 96u);
    int k = idx - tt * 96;
    int seg = k >> 5;
    int jj = (k & 31) * 2;
    r[p] = *(const uint32_t*)(base + (size_t)(w16 + tt) * NPAD + SB0 + seg * 64 + jj);
  }
}
__device__ __forceinline__ void s_write(const uint32_t r[6], float* __restrict__ sl,
                                        const float* __restrict__ bs_w,
                                        const float* __restrict__ bs_mu,
                                        const float* __restrict__ bs_var, int tid) {
#pragma unroll
  for (int p = 0; p < 6; ++p) {
    int idx = tid + p * 256;
    int tt = (int)((unsigned)idx / 96u);
    int k = idx - tt * 96;
    int seg = k >> 5;
    int jj = (k & 31) * 2;
    const float* bs = seg == 0 ? bs_w : (seg == 1 ? bs_mu : bs_var);
#pragma unroll
    for (int e = 0; e < 2; ++e) {
      int j2 = jj + e;
      if (j2 < 51) {
        float v = h2f((u16)((r[p] >> (16 * e)) & 0xffffu)) + bs[j2];
        if (seg == 2) v = __expf(fminf(fmaxf(v, -1.f), 1.f));
        sl[tt * SWP + seg * 51 + j2] = v;
      }
    }
  }
}

__global__ __launch_bounds__(256) void scan_kernel(
    const u16* __restrict__ Ch, float* __restrict__ out, float* __restrict__ carry,
    const float* __restrict__ bs_w, const float* __restrict__ bs_mu,
    const float* __restrict__ bs_var,
    int t0, int TC, int isFirst, int isLast) {
  __shared__ float slds[2][16 * SWP];   // double-buffered s-window
  int tid = threadIdx.x;
  int ij0 = blockIdx.y * 256 + tid;
  int valid = ij0 < L2Q;
  int ij = valid ? ij0 : L2Q - 1;
  int b = blockIdx.x;
  int j = (int)((unsigned)ij % 51u);
  const u16* base = Ch + (size_t)b * TC * NPAD;
  float* outb = out + (size_t)b * TQ * L2Q + ij0;
  float mu_p = 0.f, var_p = 1.f;
  if (!isFirst) {
    mu_p = carry[b * L2Q + ij];
    var_p = carry[BQ * L2Q + b * L2Q + ij];
  }
  // ring init: window 0 (dt = 0..15); 16-deep static register ring
  u32x3 ring[16];
#pragma unroll
  for (int p = 0; p < 16; ++p)
    ring[p] = *(const u32x3*)(base + (size_t)p * NPAD + 6 * ij);

  // prologue: stage s-window 0 into buffer 0
  {
    uint32_t r0[6];
    s_issue(r0, base, 0, tid);
    s_write(r0, slds[0], bs_w, bs_mu, bs_var, tid);
  }
  __syncthreads();

  int nwin = TC >> 4;
#pragma unroll 1
  for (int w = 0; w < nwin; ++w) {
    // issue next window's staging loads EARLY (land under this window's compute)
    int wn = (w + 1 < nwin) ? (w + 1) : w;   // clamp: harmless redundant loads
    uint32_t rr[6];
    s_issue(rr, base, wn * 16, tid);

    const float* sl = slds[w & 1];
#pragma unroll
    for (int tt = 0; tt < 16; ++tt) {
      int dt = w * 16 + tt;
      int t = t0 + dt;
      u32x3 cr = ring[tt];
      int dtn = dt + 16;
      if (dtn > TC - 1) dtn = TC - 1;          // clamp (harmless extra read)
      u32x3 nx = *(const u32x3*)(base + (size_t)dtn * NPAD + 6 * ij);
      Vals cur = decode_t(cr);
      cur.sw   = sl[tt * SWP + j];
      cur.smu  = sl[tt * SWP + 51 + j];
      cur.svar = sl[tt * SWP + 102 + j];
      if (tt == 0 && w == 0 && isFirst) {
        // t=0: child-merge with s0, then parent-merge with t-struct of row 1
        float mu_c, var_c;
        float sc0 = merge2<true>(cur, cur.smu, cur.svar, mu_c, var_c);
        Vals v1 = decode_t(ring[1]);
        float sp0 = merge2<false>(v1, mu_c, var_c, mu_p, var_p);
        if (valid) outb[0] = sc0 + sp0 + cur.tw + cur.sw;
      } else {
        float vsum = var_p + cur.svar;
        float rv = frcp(vsum);
        float logv = flog(vsum);
        float dmu = mu_p - cur.smu;
        float sc = -0.5f * (LOG2PI_F + logv + dmu * dmu * rv);
        float mu_c = (mu_p * cur.svar + cur.smu * var_p) * rv;
        float var_c = vsum - 0.5f * logv;
        float sp = merge2<false>(cur, mu_c, var_c, mu_p, var_p);
        if (valid) outb[(size_t)t * L2Q] = sc + sp + cur.tw + cur.sw;
      }
      ring[tt] = nx;
    }

    // write-late into the other buffer; its last readers (window w-1) all
    // passed the barrier at end of window w-1 before we got here.
    s_write(rr, slds[(w + 1) & 1], bs_w, bs_mu, bs_var, tid);
    __syncthreads();   // one barrier per window (was two)
  }
  if (!isLast && valid) {
    carry[b * L2Q + ij] = mu_p;
    carry[BQ * L2Q + b * L2Q + ij] = var_p;
  }
}

// ---------------------------------------------------------------- launch
extern "C" void kernel_launch(void* const* d_in, const int* in_sizes, int n_in,
                              void* d_out, int out_size, void* d_ws, size_t ws_size,
                              hipStream_t stream) {
  (void)in_sizes; (void)n_in; (void)out_size;
  const float* x      = (const float*)d_in[0];
  const float* Ws_w   = (const float*)d_in[1];
  const float* bs_w   = (const float*)d_in[2];
  const float* Ws_mu  = (const float*)d_in[3];
  const float* bs_mu  = (const float*)d_in[4];
  const float* Ws_var = (const float*)d_in[5];
  const float* bs_var = (const float*)d_in[6];
  const float* Wt_w   = (const float*)d_in[7];
  const float* bt_w   = (const float*)d_in[8];
  const float* Wt_mu  = (const float*)d_in[9];
  const float* bt_mu  = (const float*)d_in[10];
  const float* Wt_var = (const float*)d_in[11];
  const float* bt_var = (const float*)d_in[12];
  float* out = (float*)d_out;

  char* ws = (char*)d_ws;
  const size_t szA = (size_t)4096 * KQ * 2;
  const size_t szB = (size_t)NPAD * KQ * 2;
  const size_t szCar = ((size_t)BQ * L2Q * 2 * 4 + 255) & ~(size_t)255;
  const size_t szBias = ((size_t)NPAD * 4 + 255) & ~(size_t)255;
  u16* Abf = (u16*)ws;
  u16* BTb = (u16*)(ws + szA);
  float* carry = (float*)(ws + szA + szB);
  float* biasTab = (float*)(ws + szA + szB + szCar);
  size_t off0 = szA + szB + szCar + szBias;

  // chunk T so the fp16 C buffer fits in ws (TC=256 needs ~160 MB total)
  int TC = 256;
  while (TC > 16 && off0 + (size_t)BQ * TC * NPAD * 2 > ws_size) TC >>= 1;
  __half* Ch = (__half*)(ws + off0);
  int lgTC = 31 - __builtin_clz((unsigned)TC);
  int nch = TQ / TC;
  int nmt = (BQ * TC) / 128;        // 128-row A-tiles per chunk (>= 2)
  int nmt2 = nmt >> 1;              // 256-row M-blocks per chunk (>= 1)
  int lg_nmt2 = 31 - __builtin_clz((unsigned)nmt2);

  build_a_kernel<<<dim3((4096 * 512) / 256), dim3(256), 0, stream>>>(x, Abf, TC, lgTC, nmt);
  build_b_kernel<<<dim3(NPAD / 256, DQ / 8), dim3(256), 0, stream>>>(
      Ws_w, Ws_mu, Ws_var, Wt_w, Wt_mu, Wt_var, bt_w, bt_mu, bt_var, BTb, biasTab);
  for (int c = 0; c < nch; ++c) {
    int t0 = c * TC;
    gemm_kernel<<<dim3(128 * nmt2), dim3(256), 0, stream>>>(
        Abf, BTb, biasTab, Ch, c * nmt, lg_nmt2);
    scan_kernel<<<dim3(BQ, (L2Q + 255) / 256), dim3(256), 0, stream>>>(
        (const u16*)Ch, out, carry, bs_w, bs_mu, bs_var,
        t0, TC, c == 0 ? 1 : 0, c == nch - 1 ? 1 : 0);
  }
}

// Round 12
// 276.479 us; speedup vs baseline: 1.0564x; 1.0564x over previous
//
#include <hip/hip_runtime.h>
#include <hip/hip_fp16.h>
#include <stdint.h>

#define AS1 __attribute__((address_space(1)))
#define AS3 __attribute__((address_space(3)))

typedef unsigned short u16;
typedef __attribute__((ext_vector_type(8))) _Float16 half8;
typedef __attribute__((ext_vector_type(4))) float f32x4;
typedef __attribute__((ext_vector_type(3))) uint32_t u32x3;

#define LOG2PI_F 1.8378770664093453f

// problem constants
#define BQ   16
#define TQ   256
#define DQ   512
#define LQ   51
#define L2Q  2601
#define KQ   512      // single fp16 x . fp16 W  (xl/Wl terms ~1e-4 << fp16-C rounding)
#define NCOL   15759
#define NPAD   15872  // 124*128
// tiled operand layout (= LDS staging order): [tile][c8(0..63)][row(0..127)][8 u16]
#define TILE_U16  65536
#define TILE_U4   8192
// permuted column layout (baked into B^T row order). t-struct cols are stored
// TRANSFORMED by the gemm epilogue (bias added; fields 3/5 exp'd; field 4 as
// ofac = 0.9*tanh(0.5*u) stored directly). s-block cols stay RAW:
//   col < 15606 : 6*ij + {0:tw, 1:m0, 2:m1, 3:d0, 4:ofac, 5:d1}
//   s-blocks    : sw_raw @ SB0+j, smu_raw @ SB1+j, svar_raw @ SB2+j   (j<51)
#define NSTR 15606
#define SB0  15616
#define SB1  15680
#define SB2  15744
#define SWP  156    // scan LDS s-window pitch (floats)

__device__ __forceinline__ u16 f2h(float f) {
  union { __half h; u16 u; } cv; cv.h = __float2half(f); return cv.u;
}
__device__ __forceinline__ float frcp(float x) { return __builtin_amdgcn_rcpf(x); }
__device__ __forceinline__ float flog(float x) { return __builtin_amdgcn_logf(x) * 0.6931471805599453f; }
__device__ __forceinline__ float h2f(u16 bits) {
  union { u16 u; __half h; } cv; cv.u = bits;
  return __half2float(cv.h);
}
__device__ __forceinline__ float2 cvth2(uint32_t w) {
  return __half22float2(*(const __half2*)&w);
}

// ---------------------------------------------------------------- build A (tiled)
// single fp16: xh = fp16(x).
__global__ __launch_bounds__(256) void build_a_kernel(const float* __restrict__ x,
                                                      u16* __restrict__ A,
                                                      int TC, int lgTC, int nmt) {
  int idx = blockIdx.x * 256 + threadIdx.x;   // exactly 4096*512
  int m = idx >> 9;
  int k = idx & 511;
  float v = x[idx];
  u16 h = f2h(v);
  int b = m >> 8, t = m & 255;
  int c = t >> lgTC;                 // chunk
  int tloc = t & (TC - 1);
  int mloc = b * TC + tloc;          // chunk-local row
  int mt = mloc >> 7, r = mloc & 127;
  u16* tile = A + (size_t)(c * nmt + mt) * TILE_U16 + r * 8;
  int c8 = k >> 3, e = k & 7;
  tile[(size_t)c8 * 1024 + e] = h;
}

// ---------------------------------------------------------------- build B^T (tiled)
// R12: divergence-free thread-per-ij. Each thread owns all 6 t-fields of one
// ij: reads float4(Wt_var[k][4ij]) + float2(Wt_mu[k][2ij]) + Wt_w[k][ij] --
// consecutive lanes -> consecutive vectors (coalesced, no exec-mask serialization;
// R11's per-n switch ran 6 gather cases per wave at ~11/64 lanes each).
// Tail threads: 51 s-cols, 113 pad/gap cols. Outputs bit-identical to R11.
__global__ __launch_bounds__(256) void build_b_kernel(
    const float* __restrict__ Ws_w, const float* __restrict__ Ws_mu,
    const float* __restrict__ Ws_var, const float* __restrict__ Wt_w,
    const float* __restrict__ Wt_mu, const float* __restrict__ Wt_var,
    const float* __restrict__ bt_w, const float* __restrict__ bt_mu,
    const float* __restrict__ bt_var, u16* __restrict__ BT,
    float* __restrict__ biasTab) {
  int gid = blockIdx.x * 256 + threadIdx.x;
  int c8 = blockIdx.y;               // k-octet
  int kb = c8 * 8;
  uint4* tbase = (uint4*)BT;
  if (gid < L2Q) {
    int ij = gid;
    union { u16 u[8]; uint4 v; } H[6];
#pragma unroll
    for (int t = 0; t < 8; ++t) {
      int k = kb + t;
      float4 v4 = *(const float4*)(Wt_var + (size_t)k * (4 * L2Q) + 4 * ij);
      float2 m2 = *(const float2*)(Wt_mu + (size_t)k * (2 * L2Q) + 2 * ij);
      float  w1 = Wt_w[(size_t)k * L2Q + ij];
      H[0].u[t] = f2h(w1);
      H[1].u[t] = f2h(m2.x);
      H[2].u[t] = f2h(m2.y);
      H[3].u[t] = f2h(v4.x);
      H[4].u[t] = f2h(v4.y + v4.z);
      H[5].u[t] = f2h(v4.w);
    }
#pragma unroll
    for (int r = 0; r < 6; ++r) {
      int n = 6 * ij + r;
      tbase[(size_t)(n >> 7) * TILE_U4 + c8 * 128 + (n & 127)] = H[r].v;
    }
    if (blockIdx.y == 0) {
      float4 bv = *(const float4*)(bt_var + 4 * ij);
      float2 bm = *(const float2*)(bt_mu + 2 * ij);
      biasTab[6 * ij + 0] = bt_w[ij];
      biasTab[6 * ij + 1] = bm.x;
      biasTab[6 * ij + 2] = bm.y;
      biasTab[6 * ij + 3] = bv.x;
      biasTab[6 * ij + 4] = bv.y + bv.z;
      biasTab[6 * ij + 5] = bv.w;
    }
  } else if (gid < L2Q + LQ) {
    int j = gid - L2Q;
    union { u16 u[8]; uint4 v; } S[3];
#pragma unroll
    for (int t = 0; t < 8; ++t) {
      int k = kb + t;
      S[0].u[t] = f2h(Ws_w[(size_t)k * LQ + j]);
      S[1].u[t] = f2h(Ws_mu[(size_t)k * LQ + j]);
      S[2].u[t] = f2h(Ws_var[(size_t)k * LQ + j]);
    }
#pragma unroll
    for (int r = 0; r < 3; ++r) {
      int n = SB0 + r * 64 + j;     // SB1-SB0 = SB2-SB1 = 64
      tbase[(size_t)(n >> 7) * TILE_U4 + c8 * 128 + (n & 127)] = S[r].v;
    }
    if (blockIdx.y == 0) {
      biasTab[SB0 + j] = 0.f; biasTab[SB1 + j] = 0.f; biasTab[SB2 + j] = 0.f;
    }
  } else if (gid < L2Q + LQ + 113) {
    int idx = gid - (L2Q + LQ);
    int col;
    if (idx < 10)      col = NSTR + idx;          // 15606..15615
    else if (idx < 23) col = 15667 + (idx - 10);  // gap SB0-block
    else if (idx < 36) col = 15731 + (idx - 23);  // gap SB1-block
    else               col = 15795 + (idx - 36);  // 15795..15871
    uint4 z; z.x = 0; z.y = 0; z.z = 0; z.w = 0;
    tbase[(size_t)(col >> 7) * TILE_U4 + c8 * 128 + (col & 127)] = z;
    if (blockIdx.y == 0) biasTab[col] = 0.f;
  }
}

// ---------------------------------------------------------------- GEMM
// K=512 single-fp16. 256x128 block (wave 128x64), ring-3 BK=32 slots,
// stage-ahead-1, counted vmcnt(6), raw s_barrier, setprio, 16x16x32 f16.
// Epilogue fuses bias + field transform; fc INNERMOST (R11: fixed 1.9x HBM
// write amplification; WRITE_SIZE now exactly logical 130MB).
__global__ __launch_bounds__(256, 2) void gemm_kernel(
    const u16* __restrict__ A, const u16* __restrict__ BT,
    const float* __restrict__ biasTab,
    __half* __restrict__ C, int tile0, int lg_nmt2) {
  const int lin = blockIdx.x;
  const int xcd = lin & 7;
  const int s = lin >> 3;
  const int mb = lg_nmt2 < 2 ? lg_nmt2 : 2;
  const int msub = s & ((1 << mb) - 1);
  const int ntsel = (s >> mb) & 15;
  const int mset = s >> (mb + 4);
  const int mtile2 = (mset << mb) + msub;      // 256-row M-block index
  const int ntile = (ntsel << 3) + xcd;
  if (ntile >= 124) return;

  __shared__ uint4 ring[3][1536];   // 72 KB -> 2 blocks/CU
  const int tid = threadIdx.x;
  const int lane = tid & 63;
  const int wave = tid >> 6;
  const int wM = wave >> 1;        // which 128-row A half-tile
  const int wN = wave & 1;         // which 64-col B half
  const int q4 = lane >> 4;
  const int c16 = lane & 15;

  const uint4* At0 = (const uint4*)A + (size_t)(tile0 + mtile2 * 2) * TILE_U4;
  const uint4* At1 = At0 + TILE_U4;
  const uint4* Bt  = (const uint4*)BT + (size_t)ntile * TILE_U4;

  f32x4 acc[8][4];
#pragma unroll
  for (int a_ = 0; a_ < 8; ++a_)
#pragma unroll
    for (int b_ = 0; b_ < 4; ++b_) acc[a_][b_] = (f32x4){0.f, 0.f, 0.f, 0.f};

  AS3 uint4* rg = (AS3 uint4*)&ring[0][0];

#define STAGE_W(slot, h)                                                        \
  {                                                                             \
    _Pragma("unroll")                                                           \
    for (int ss_ = 0; ss_ < 2; ++ss_) {                                         \
      int ca_ = wave * 2 + ss_;                                                 \
      __builtin_amdgcn_global_load_lds(                                         \
          (const AS1 void*)(At0 + (h) * 512 + ca_ * 64 + lane),                 \
          (AS3 void*)(rg + (slot) * 1536 + ca_ * 64), 16, 0, 0);                \
      __builtin_amdgcn_global_load_lds(                                         \
          (const AS1 void*)(At1 + (h) * 512 + ca_ * 64 + lane),                 \
          (AS3 void*)(rg + (slot) * 1536 + 512 + ca_ * 64), 16, 0, 0);          \
      __builtin_amdgcn_global_load_lds(                                         \
          (const AS1 void*)(Bt + (h) * 512 + ca_ * 64 + lane),                  \
          (AS3 void*)(rg + (slot) * 1536 + 1024 + ca_ * 64), 16, 0, 0);         \
    }                                                                           \
  }

  STAGE_W(0, 0);

  int cur = 0;
  for (int h = 0; h < 16; ++h) {
    int nxt = cur + 1; if (nxt == 3) nxt = 0;
    int hs = (h + 1 < 16) ? (h + 1) : 15;
    STAGE_W(nxt, hs);
    asm volatile("s_waitcnt vmcnt(6)" ::: "memory");
    __builtin_amdgcn_s_barrier();   // all waves' window-h loads now visible

    const uint4* sa = &ring[cur][wM * 512];
    const uint4* sb = &ring[cur][1024];
    half8 af[8], bfv[4];
#pragma unroll
    for (int f = 0; f < 8; ++f)
      af[f] = *(const half8*)&sa[q4 * 128 + f * 16 + c16];
#pragma unroll
    for (int g = 0; g < 4; ++g)
      bfv[g] = *(const half8*)&sb[q4 * 128 + wN * 64 + g * 16 + c16];
    __builtin_amdgcn_s_setprio(1);
#pragma unroll
    for (int fr = 0; fr < 8; ++fr)
#pragma unroll
      for (int fc = 0; fc < 4; ++fc)
        acc[fr][fc] = __builtin_amdgcn_mfma_f32_16x16x32_f16(af[fr], bfv[fc],
                                                             acc[fr][fc], 0, 0, 0);
    __builtin_amdgcn_s_setprio(0);
    cur = nxt;
  }
#undef STAGE_W

  // epilogue: fused bias + field transform, fp16 store, fc innermost.
  int colv[4]; float biasv[4], clv[4]; int dDv[4], dOv[4];
#pragma unroll
  for (int fc = 0; fc < 4; ++fc) {
    int col = ntile * 128 + wN * 64 + fc * 16 + c16;
    colv[fc] = col;
    biasv[fc] = biasTab[col];
    unsigned uc = (unsigned)col;
    unsigned ij6 = uc / 6u;
    int r = (int)(uc - 6u * ij6);
    dDv[fc] = (col < NSTR) && (r == 3 || r == 5);
    dOv[fc] = (col < NSTR) && (r == 4);
    clv[fc] = dOv[fc] ? 11.f : 1.f;
  }
#pragma unroll
  for (int fr = 0; fr < 8; ++fr) {
    int growb = (mtile2 * 2 + wM) * 128 + fr * 16 + q4 * 4;
#pragma unroll
    for (int i = 0; i < 4; ++i) {
      size_t rowoff = (size_t)(growb + i) * NPAD;
#pragma unroll
      for (int fc = 0; fc < 4; ++fc) {
        float v = acc[fr][fc][i] + biasv[fc];
        float e = __expf(fminf(fmaxf(v, -clv[fc]), clv[fc]));
        float of = 0.9f * (e - 1.f) * frcp(e + 1.f);
        v = dDv[fc] ? e : (dOv[fc] ? of : v);
        C[rowoff + colv[fc]] = __float2half(v);
      }
    }
  }
}

// ---------------------------------------------------------------- scan
struct Vals { float sw, smu, svar, tw, m0, m1, d0, ofac, d1; };

// log-combined merge2: the four flog() of the original collapse to one
// flog(det*nvar*den*la)  (all factors > 0; derivation checked vs original).
template <bool CHILD>
__device__ __forceinline__ float merge2(const Vals& v, float nmu, float nvar,
                                        float& mu_n, float& var_n) {
  float off = v.ofac * __builtin_amdgcn_sqrtf(v.d0 * v.d1);
  float det = fmaf(v.d0, v.d1, -off * off);
  float inv = frcp(det);
  float a = v.d1 * inv, bo = -off * inv, d = v.d0 * inv;
  float e0 = a * v.m0 + bo * v.m1;
  float e1 = bo * v.m0 + d * v.m1;
  float quad1 = e0 * e0 * v.d0 + 2.f * e0 * e1 * off + e1 * e1 * v.d1;
  float l2 = frcp(nvar);
  float eta2 = nmu * l2;
  float den, keep, es, la;
  if (CHILD) { den = d + l2; keep = e0; es = e1 + eta2; }
  else       { den = a + l2; keep = e1; es = e0 + eta2; }
  float rden = frcp(den);
  if (CHILD) la = a - bo * bo * rden;
  else       la = d - bo * bo * rden;
  float etan = keep - bo * rden * es;
  var_n = frcp(la);
  mu_n = var_n * etan;
  float lp = det * nvar;
  lp *= den;
  lp *= la;
  return -0.5f * (LOG2PI_F + flog(lp) + quad1 + nmu * eta2 - es * es * rden -
                  etan * etan * var_n);
}

// decode: all fields pre-transformed by the gemm epilogue -> pure converts.
__device__ __forceinline__ Vals decode_t(u32x3 cr) {
  float2 p0 = cvth2(cr.x);
  float2 p1 = cvth2(cr.y);
  float2 p2 = cvth2(cr.z);
  Vals cur;
  cur.tw = p0.x;
  cur.m0 = p0.y;
  cur.m1 = p1.x;
  cur.d0 = p1.y;
  cur.ofac = p2.x;                      // 0.9*tanh stored directly
  cur.d1 = p2.y;
  cur.sw = 0.f; cur.smu = 0.f; cur.svar = 1.f;
  return cur;
}

// s-window staging, split issue-early / write-late (T14).
// 16 rows x 3 segs x 64 cols (51 valid) = 16*96 u32 = 1536 = 6/thread.
__device__ __forceinline__ void s_issue(uint32_t r[6], const u16* __restrict__ base,
                                        int w16, int tid) {
#pragma unroll
  for (int p = 0; p < 6; ++p) {
    int idx = tid + p * 256;
    int tt = (int)((unsigned)idx / 96u);
    int k = idx - tt * 96;
    int seg = k >> 5;
    int jj = (k & 31) * 2;
    r[p] = *(const uint32_t*)(base + (size_t)(w16 + tt) * NPAD + SB0 + seg * 64 + jj);
  }
}
__device__ __forceinline__ void s_write(const uint32_t r[6], float* __restrict__ sl,
                                        const float* __restrict__ bs_w,
                                        const float* __restrict__ bs_mu,
                                        const float* __restrict__ bs_var, int tid) {
#pragma unroll
  for (int p = 0; p < 6; ++p) {
    int idx = tid + p * 256;
    int tt = (int)((unsigned)idx / 96u);
    int k = idx - tt * 96;
    int seg = k >> 5;
    int jj = (k & 31) * 2;
    const float* bs = seg == 0 ? bs_w : (seg == 1 ? bs_mu : bs_var);
#pragma unroll
    for (int e = 0; e < 2; ++e) {
      int j2 = jj + e;
      if (j2 < 51) {
        float v = h2f((u16)((r[p] >> (16 * e)) & 0xffffu)) + bs[j2];
        if (seg == 2) v = __expf(fminf(fmaxf(v, -1.f), 1.f));
        sl[tt * SWP + seg * 51 + j2] = v;
      }
    }
  }
}

__global__ __launch_bounds__(256) void scan_kernel(
    const u16* __restrict__ Ch, float* __restrict__ out, float* __restrict__ carry,
    const float* __restrict__ bs_w, const float* __restrict__ bs_mu,
    const float* __restrict__ bs_var,
    int t0, int TC, int isFirst, int isLast) {
  __shared__ float slds[2][16 * SWP];   // double-buffered s-window
  int tid = threadIdx.x;
  int ij0 = blockIdx.y * 256 + tid;
  int valid = ij0 < L2Q;
  int ij = valid ? ij0 : L2Q - 1;
  int b = blockIdx.x;
  int j = (int)((unsigned)ij % 51u);
  const u16* base = Ch + (size_t)b * TC * NPAD;
  float* outb = out + (size_t)b * TQ * L2Q + ij0;
  float mu_p = 0.f, var_p = 1.f;
  if (!isFirst) {
    mu_p = carry[b * L2Q + ij];
    var_p = carry[BQ * L2Q + b * L2Q + ij];
  }
  // ring init: window 0 (dt = 0..15); 16-deep static register ring
  u32x3 ring[16];
#pragma unroll
  for (int p = 0; p < 16; ++p)
    ring[p] = *(const u32x3*)(base + (size_t)p * NPAD + 6 * ij);

  // prologue: stage s-window 0 into buffer 0
  {
    uint32_t r0[6];
    s_issue(r0, base, 0, tid);
    s_write(r0, slds[0], bs_w, bs_mu, bs_var, tid);
  }
  __syncthreads();

  int nwin = TC >> 4;
#pragma unroll 1
  for (int w = 0; w < nwin; ++w) {
    // issue next window's staging loads EARLY (land under this window's compute)
    int wn = (w + 1 < nwin) ? (w + 1) : w;   // clamp: harmless redundant loads
    uint32_t rr[6];
    s_issue(rr, base, wn * 16, tid);

    const float* sl = slds[w & 1];
#pragma unroll
    for (int tt = 0; tt < 16; ++tt) {
      int dt = w * 16 + tt;
      int t = t0 + dt;
      u32x3 cr = ring[tt];
      int dtn = dt + 16;
      if (dtn > TC - 1) dtn = TC - 1;          // clamp (harmless extra read)
      u32x3 nx = *(const u32x3*)(base + (size_t)dtn * NPAD + 6 * ij);
      Vals cur = decode_t(cr);
      cur.sw   = sl[tt * SWP + j];
      cur.smu  = sl[tt * SWP + 51 + j];
      cur.svar = sl[tt * SWP + 102 + j];
      if (tt == 0 && w == 0 && isFirst) {
        // t=0: child-merge with s0, then parent-merge with t-struct of row 1
        float mu_c, var_c;
        float sc0 = merge2<true>(cur, cur.smu, cur.svar, mu_c, var_c);
        Vals v1 = decode_t(ring[1]);
        float sp0 = merge2<false>(v1, mu_c, var_c, mu_p, var_p);
        if (valid) outb[0] = sc0 + sp0 + cur.tw + cur.sw;
      } else {
        float vsum = var_p + cur.svar;
        float rv = frcp(vsum);
        float logv = flog(vsum);
        float dmu = mu_p - cur.smu;
        float sc = -0.5f * (LOG2PI_F + logv + dmu * dmu * rv);
        float mu_c = (mu_p * cur.svar + cur.smu * var_p) * rv;
        float var_c = vsum - 0.5f * logv;
        float sp = merge2<false>(cur, mu_c, var_c, mu_p, var_p);
        if (valid) outb[(size_t)t * L2Q] = sc + sp + cur.tw + cur.sw;
      }
      ring[tt] = nx;
    }

    // write-late into the other buffer; its last readers (window w-1) all
    // passed the barrier at end of window w-1 before we got here.
    s_write(rr, slds[(w + 1) & 1], bs_w, bs_mu, bs_var, tid);
    __syncthreads();   // one barrier per window (was two)
  }
  if (!isLast && valid) {
    carry[b * L2Q + ij] = mu_p;
    carry[BQ * L2Q + b * L2Q + ij] = var_p;
  }
}

// ---------------------------------------------------------------- launch
extern "C" void kernel_launch(void* const* d_in, const int* in_sizes, int n_in,
                              void* d_out, int out_size, void* d_ws, size_t ws_size,
                              hipStream_t stream) {
  (void)in_sizes; (void)n_in; (void)out_size;
  const float* x      = (const float*)d_in[0];
  const float* Ws_w   = (const float*)d_in[1];
  const float* bs_w   = (const float*)d_in[2];
  const float* Ws_mu  = (const float*)d_in[3];
  const float* bs_mu  = (const float*)d_in[4];
  const float* Ws_var = (const float*)d_in[5];
  const float* bs_var = (const float*)d_in[6];
  const float* Wt_w   = (const float*)d_in[7];
  const float* bt_w   = (const float*)d_in[8];
  const float* Wt_mu  = (const float*)d_in[9];
  const float* bt_mu  = (const float*)d_in[10];
  const float* Wt_var = (const float*)d_in[11];
  const float* bt_var = (const float*)d_in[12];
  float* out = (float*)d_out;

  char* ws = (char*)d_ws;
  const size_t szA = (size_t)4096 * KQ * 2;
  const size_t szB = (size_t)NPAD * KQ * 2;
  const size_t szCar = ((size_t)BQ * L2Q * 2 * 4 + 255) & ~(size_t)255;
  const size_t szBias = ((size_t)NPAD * 4 + 255) & ~(size_t)255;
  u16* Abf = (u16*)ws;
  u16* BTb = (u16*)(ws + szA);
  float* carry = (float*)(ws + szA + szB);
  float* biasTab = (float*)(ws + szA + szB + szCar);
  size_t off0 = szA + szB + szCar + szBias;

  // chunk T so the fp16 C buffer fits in ws (TC=256 needs ~160 MB total)
  int TC = 256;
  while (TC > 16 && off0 + (size_t)BQ * TC * NPAD * 2 > ws_size) TC >>= 1;
  __half* Ch = (__half*)(ws + off0);
  int lgTC = 31 - __builtin_clz((unsigned)TC);
  int nch = TQ / TC;
  int nmt = (BQ * TC) / 128;        // 128-row A-tiles per chunk (>= 2)
  int nmt2 = nmt >> 1;              // 256-row M-blocks per chunk (>= 1)
  int lg_nmt2 = 31 - __builtin_clz((unsigned)nmt2);

  build_a_kernel<<<dim3((4096 * 512) / 256), dim3(256), 0, stream>>>(x, Abf, TC, lgTC, nmt);
  build_b_kernel<<<dim3(11, DQ / 8), dim3(256), 0, stream>>>(
      Ws_w, Ws_mu, Ws_var, Wt_w, Wt_mu, Wt_var, bt_w, bt_mu, bt_var, BTb, biasTab);
  for (int c = 0; c < nch; ++c) {
    int t0 = c * TC;
    gemm_kernel<<<dim3(128 * nmt2), dim3(256), 0, stream>>>(
        Abf, BTb, biasTab, Ch, c * nmt, lg_nmt2);
    scan_kernel<<<dim3(BQ, (L2Q + 255) / 256), dim3(256), 0, stream>>>(
        (const u16*)Ch, out, carry, bs_w, bs_mu, bs_var,
        t0, TC, c == 0 ? 1 : 0, c == nch - 1 ? 1 : 0);
  }
}